// Round 2
// baseline (1357.665 us; speedup 1.0000x reference)
//
#include <hip/hip_runtime.h>
#include <math.h>

#define N 8192
#define IN_F 512
#define OUTF 64
#define TI 8          // rows per wave in k_attn
#define JSPLIT 4
#define JRANGE (N / JSPLIT)

// workspace layout (in floats) — total ~10.7 MB (same as round 1)
#define OFF_H    0u          // 8192*64   = 524288
#define OFF_S    524288u     // 8192
#define OFF_T    532480u     // 8192
#define OFF_TMAX 540672u     // 1 uint (padded to 16)
#define OFF_SP   540688u     // JSPLIT*8192 = 32768
#define OFF_ACC  573456u     // JSPLIT*524288 = 2097152

__device__ __forceinline__ unsigned enc_f32(float f) {
  unsigned b = __float_as_uint(f);
  return b ^ ((unsigned)((int)b >> 31) | 0x80000000u);
}

// ---------------------------------------------------------------------------
// K1: h = input @ W, s = h@a1, t = h@a2.  4 rows per wave, 2048 blocks.
// ---------------------------------------------------------------------------
__global__ __launch_bounds__(64) void k_precompute(
    const float* __restrict__ input, const float* __restrict__ W,
    const float* __restrict__ a, float* __restrict__ h,
    float* __restrict__ s, float* __restrict__ t) {
  const int lane = threadIdx.x;
  const int i0 = blockIdx.x * 4;

  float acc[4] = {0.f, 0.f, 0.f, 0.f};

  for (int c = 0; c < IN_F; c += 4) {
    const float w0 = W[(c + 0) * OUTF + lane];
    const float w1 = W[(c + 1) * OUTF + lane];
    const float w2 = W[(c + 2) * OUTF + lane];
    const float w3 = W[(c + 3) * OUTF + lane];
    #pragma unroll
    for (int r = 0; r < 4; r++) {
      const float4 iv = *(const float4*)(input + (size_t)(i0 + r) * IN_F + c);
      acc[r] += iv.x * w0 + iv.y * w1 + iv.z * w2 + iv.w * w3;
    }
  }

  const float a1v = a[lane];
  const float a2v = a[OUTF + lane];
  #pragma unroll
  for (int r = 0; r < 4; r++) {
    h[(size_t)(i0 + r) * OUTF + lane] = acc[r];
    float sv = acc[r] * a1v;
    float tv = acc[r] * a2v;
    #pragma unroll
    for (int off = 1; off < 64; off <<= 1) {
      sv += __shfl_xor(sv, off);
      tv += __shfl_xor(tv, off);
    }
    if (lane == 0) {
      s[i0 + r] = sv;
      t[i0 + r] = tv;
    }
  }
}

// ---------------------------------------------------------------------------
// K1.5: tmax via 16-block atomicMax on monotone-encoded uint (memset-0 init).
// ---------------------------------------------------------------------------
__global__ __launch_bounds__(512) void k_tmax(const float* __restrict__ t,
                                              unsigned* __restrict__ tmax) {
  __shared__ float red[8];
  const int tid = threadIdx.x;
  float m = t[blockIdx.x * 512 + tid];
  #pragma unroll
  for (int off = 1; off < 64; off <<= 1) m = fmaxf(m, __shfl_xor(m, off));
  if ((tid & 63) == 0) red[tid >> 6] = m;
  __syncthreads();
  if (tid == 0) {
    #pragma unroll
    for (int w = 1; w < 8; w++) m = fmaxf(m, red[w]);
    atomicMax(tmax, enc_f32(m));
  }
}

// ---------------------------------------------------------------------------
// K2: masked-softmax attention partials. One wave per block, TI=8 rows,
// software-pipelined adj prefetch, chunked h double-buffer (no hreg[64]).
// ---------------------------------------------------------------------------
__global__ __launch_bounds__(64, 4) void k_attn(
    const float* __restrict__ h, const float* __restrict__ s,
    const float* __restrict__ t, const unsigned* __restrict__ tmaxp,
    const float* __restrict__ W_si, const float* __restrict__ W_ei,
    const float* __restrict__ adj_ad, const int* __restrict__ adj,
    float* __restrict__ SP, float* __restrict__ accP) {
  const int lane = threadIdx.x;
  const int wid = blockIdx.x;
  const int split = wid & (JSPLIT - 1);
  const int i0 = (wid >> 2) * TI;
  const int jb = split * JRANGE;

  const float aei = fabsf(W_ei[0]);
  const float asi = fabsf(W_si[0]);
  const unsigned te = *tmaxp;
  const float tm = __uint_as_float((te & 0x80000000u) ? (te ^ 0x80000000u) : ~te);

  float sr[TI], Mr[TI], S[TI], acc[TI];
  #pragma unroll
  for (int r = 0; r < TI; r++) {
    sr[r] = s[i0 + r];
    const float xm = sr[r] + tm;
    Mr[r] = aei * fmaxf(xm, 0.2f * xm) + asi;  // upper bound on e over row
    S[r] = 0.f;
    acc[r] = 0.f;
  }

  // pT[jj][r], r-chunks XOR-swizzled: phys = jj*8 + ((r>>2)^((jj>>2)&1))*4 + (r&3)
  __shared__ __align__(16) float pT[64 * TI];
  const int swl = (lane >> 2) & 1;

  // ---- prefetch tile 0 ----
  float pa[TI];
  int pmk[TI];
  float tl = t[jb + lane];
  #pragma unroll
  for (int r = 0; r < TI; r++) {
    const size_t gidx = (size_t)(i0 + r) * N + jb + lane;
    pa[r] = adj_ad[gidx];
    pmk[r] = adj[gidx];
  }

  for (int jt = 0; jt < JRANGE; jt += 64) {
    const int j0 = jb + jt;

    // ---- Phase A: compute p from prefetched regs, store to LDS ----
    float p[TI];
    #pragma unroll
    for (int r = 0; r < TI; r++) {
      const float x = sr[r] + tl;
      const float e = aei * fmaxf(x, 0.2f * x) + asi * pa[r];
      p[r] = (pmk[r] > 0) ? __expf(e - Mr[r]) : 0.f;
      S[r] += p[r];
    }
    *(float4*)&pT[lane * TI + ((0 ^ swl) << 2)] = make_float4(p[0], p[1], p[2], p[3]);
    *(float4*)&pT[lane * TI + ((1 ^ swl) << 2)] = make_float4(p[4], p[5], p[6], p[7]);

    // ---- prefetch next tile (has all of Phase B to land) ----
    if (jt + 64 < JRANGE) {
      const int jn = j0 + 64;
      tl = t[jn + lane];
      #pragma unroll
      for (int r = 0; r < TI; r++) {
        const size_t gidx = (size_t)(i0 + r) * N + jn + lane;
        pa[r] = adj_ad[gidx];
        pmk[r] = adj[gidx];
      }
    }

    // ---- Phase B: acc[r] += p[r][jj] * h[jj][lane], h in 16-chunks ----
    float hv[32];
    #pragma unroll
    for (int jl = 0; jl < 16; jl++)
      hv[jl] = h[(size_t)(j0 + jl) * OUTF + lane];

    #pragma unroll
    for (int c = 0; c < 4; c++) {
      const int cur = (c & 1) * 16;
      const int nxt = ((c + 1) & 1) * 16;
      if (c < 3) {
        #pragma unroll
        for (int jl = 0; jl < 16; jl++)
          hv[nxt + jl] = h[(size_t)(j0 + (c + 1) * 16 + jl) * OUTF + lane];
      }
      #pragma unroll
      for (int jl = 0; jl < 16; jl++) {
        const int jj = c * 16 + jl;
        const int sw = (jj >> 2) & 1;
        const float4 p0 = *(const float4*)&pT[jj * TI + ((0 ^ sw) << 2)];
        const float4 p1 = *(const float4*)&pT[jj * TI + ((1 ^ sw) << 2)];
        const float hh = hv[cur + jl];
        acc[0] += p0.x * hh;
        acc[1] += p0.y * hh;
        acc[2] += p0.z * hh;
        acc[3] += p0.w * hh;
        acc[4] += p1.x * hh;
        acc[5] += p1.y * hh;
        acc[6] += p1.z * hh;
        acc[7] += p1.w * hh;
      }
    }
  }

  // ---- epilogue: reduce S, write partials ----
  #pragma unroll
  for (int r = 0; r < TI; r++) {
    float sv = S[r];
    #pragma unroll
    for (int off = 1; off < 64; off <<= 1) sv += __shfl_xor(sv, off);
    if (lane == 0) SP[(size_t)split * N + i0 + r] = sv;
    accP[(size_t)split * (N * OUTF) + (size_t)(i0 + r) * OUTF + lane] = acc[r];
  }
}

// ---------------------------------------------------------------------------
// K3: combine j-split partials, normalize, elu.
// ---------------------------------------------------------------------------
__global__ __launch_bounds__(256) void k_combine(const float* __restrict__ accP,
                                                 const float* __restrict__ SP,
                                                 float* __restrict__ out) {
  const int idx = blockIdx.x * 256 + threadIdx.x;
  const int i = idx >> 6;
  float num = 0.f, den = 0.f;
  #pragma unroll
  for (int sp = 0; sp < JSPLIT; sp++) {
    num += accP[(size_t)sp * (N * OUTF) + idx];
    den += SP[(size_t)sp * N + i];
  }
  const float x = num / den;
  out[idx] = x > 0.f ? x : expm1f(x);
}

// ---------------------------------------------------------------------------
extern "C" void kernel_launch(void* const* d_in, const int* in_sizes, int n_in,
                              void* d_out, int out_size, void* d_ws, size_t ws_size,
                              hipStream_t stream) {
  const float* input  = (const float*)d_in[0];
  const float* W      = (const float*)d_in[1];
  const float* a      = (const float*)d_in[2];
  const float* W_si   = (const float*)d_in[3];
  const float* W_ei   = (const float*)d_in[4];
  const float* adj_ad = (const float*)d_in[5];
  const int*   adj    = (const int*)d_in[6];
  float* out = (float*)d_out;
  float* ws  = (float*)d_ws;

  float* h        = ws + OFF_H;
  float* s        = ws + OFF_S;
  float* t        = ws + OFF_T;
  unsigned* tmax  = (unsigned*)(ws + OFF_TMAX);
  float* SP       = ws + OFF_SP;
  float* accP     = ws + OFF_ACC;

  hipMemsetAsync(tmax, 0, 4, stream);
  k_precompute<<<N / 4, 64, 0, stream>>>(input, W, a, h, s, t);
  k_tmax<<<N / 512, 512, 0, stream>>>(t, tmax);
  k_attn<<<(N / TI) * JSPLIT, 64, 0, stream>>>(h, s, t, tmax, W_si, W_ei,
                                               adj_ad, adj, SP, accP);
  k_combine<<<(N * OUTF) / 256, 256, 0, stream>>>(accP, SP, out);
}

// Round 3
// 935.439 us; speedup vs baseline: 1.4514x; 1.4514x over previous
//
#include <hip/hip_runtime.h>
#include <math.h>

#define N 8192
#define IN_F 512
#define OUTF 64
#define TI 16         // rows per wave in k_attn
#define JSPLIT 4
#define JRANGE (N / JSPLIT)

// workspace layout (in floats) — total ~10.7 MB
#define OFF_H    0u          // 8192*64   = 524288
#define OFF_S    524288u     // 8192
#define OFF_T    532480u     // 8192
#define OFF_TMAX 540672u     // 1 uint (padded to 16)
#define OFF_SP   540688u     // JSPLIT*8192 = 32768
#define OFF_ACC  573456u     // JSPLIT*524288 = 2097152

__device__ __forceinline__ unsigned enc_f32(float f) {
  unsigned b = __float_as_uint(f);
  return b ^ ((unsigned)((int)b >> 31) | 0x80000000u);
}

// ---------------------------------------------------------------------------
// K1: h = input @ W, s = h@a1, t = h@a2.  4 rows per wave, 2048 blocks.
// (measured: tiny — all non-k_attn time is the harness input-restore)
// ---------------------------------------------------------------------------
__global__ __launch_bounds__(64) void k_precompute(
    const float* __restrict__ input, const float* __restrict__ W,
    const float* __restrict__ a, float* __restrict__ h,
    float* __restrict__ s, float* __restrict__ t) {
  const int lane = threadIdx.x;
  const int i0 = blockIdx.x * 4;

  float acc[4] = {0.f, 0.f, 0.f, 0.f};

  for (int c = 0; c < IN_F; c += 4) {
    const float w0 = W[(c + 0) * OUTF + lane];
    const float w1 = W[(c + 1) * OUTF + lane];
    const float w2 = W[(c + 2) * OUTF + lane];
    const float w3 = W[(c + 3) * OUTF + lane];
    #pragma unroll
    for (int r = 0; r < 4; r++) {
      const float4 iv = *(const float4*)(input + (size_t)(i0 + r) * IN_F + c);
      acc[r] += iv.x * w0 + iv.y * w1 + iv.z * w2 + iv.w * w3;
    }
  }

  const float a1v = a[lane];
  const float a2v = a[OUTF + lane];
  #pragma unroll
  for (int r = 0; r < 4; r++) {
    h[(size_t)(i0 + r) * OUTF + lane] = acc[r];
    float sv = acc[r] * a1v;
    float tv = acc[r] * a2v;
    #pragma unroll
    for (int off = 1; off < 64; off <<= 1) {
      sv += __shfl_xor(sv, off);
      tv += __shfl_xor(tv, off);
    }
    if (lane == 0) {
      s[i0 + r] = sv;
      t[i0 + r] = tv;
    }
  }
}

// ---------------------------------------------------------------------------
// K1.5: tmax via atomicMax on monotone-encoded uint (memset-0 init).
// ---------------------------------------------------------------------------
__global__ __launch_bounds__(512) void k_tmax(const float* __restrict__ t,
                                              unsigned* __restrict__ tmax) {
  __shared__ float red[8];
  const int tid = threadIdx.x;
  float m = t[blockIdx.x * 512 + tid];
  #pragma unroll
  for (int off = 1; off < 64; off <<= 1) m = fmaxf(m, __shfl_xor(m, off));
  if ((tid & 63) == 0) red[tid >> 6] = m;
  __syncthreads();
  if (tid == 0) {
    #pragma unroll
    for (int w = 1; w < 8; w++) m = fmaxf(m, red[w]);
    atomicMax(tmax, enc_f32(m));
  }
}

// ---------------------------------------------------------------------------
// K2: masked-softmax attention partials. Round-1 structure (TI=16, hreg[64])
// + register prefetch of next tile's adj/adj_ad/t.
// __launch_bounds__(64,2): 256-VGPR cap — ~196 live, NO spills (round-2 bug).
// ---------------------------------------------------------------------------
__global__ __launch_bounds__(64, 2) void k_attn(
    const float* __restrict__ h, const float* __restrict__ s,
    const float* __restrict__ t, const unsigned* __restrict__ tmaxp,
    const float* __restrict__ W_si, const float* __restrict__ W_ei,
    const float* __restrict__ adj_ad, const int* __restrict__ adj,
    float* __restrict__ SP, float* __restrict__ accP) {
  const int lane = threadIdx.x;
  const int wid = blockIdx.x;
  const int split = wid & (JSPLIT - 1);
  const int i0 = (wid >> 2) * TI;
  const int jb = split * JRANGE;

  const float aei = fabsf(W_ei[0]);
  const float asi = fabsf(W_si[0]);
  const unsigned te = *tmaxp;
  const float tm = __uint_as_float((te & 0x80000000u) ? (te ^ 0x80000000u) : ~te);

  float sr[TI], Mr[TI], S[TI], acc[TI];
  #pragma unroll
  for (int r = 0; r < TI; r++) {
    sr[r] = s[i0 + r];
    const float xm = sr[r] + tm;
    Mr[r] = aei * fmaxf(xm, 0.2f * xm) + asi;  // upper bound on e over row
    S[r] = 0.f;
    acc[r] = 0.f;
  }

  // pT[jj][r], 4-float chunks XOR-swizzled (round-1 verified layout)
  __shared__ __align__(16) float pT[64 * TI];
  const int swl = (lane >> 1) & 3;

  // ---- prefetch tile 0 into registers ----
  float pa[TI];
  int pmk[TI];
  float tl = t[jb + lane];
  #pragma unroll
  for (int r = 0; r < TI; r++) {
    const size_t gidx = (size_t)(i0 + r) * N + jb + lane;
    pa[r] = adj_ad[gidx];
    pmk[r] = adj[gidx];
  }

  for (int jt = 0; jt < JRANGE; jt += 64) {
    const int j0 = jb + jt;

    // ---- Phase A: p from prefetched regs (pure VALU), store to LDS ----
    float p[TI];
    #pragma unroll
    for (int r = 0; r < TI; r++) {
      const float x = sr[r] + tl;
      const float e = aei * fmaxf(x, 0.2f * x) + asi * pa[r];
      p[r] = (pmk[r] > 0) ? __expf(e - Mr[r]) : 0.f;
      S[r] += p[r];
    }
    #pragma unroll
    for (int ch = 0; ch < 4; ch++) {
      *(float4*)&pT[lane * TI + ((ch ^ swl) << 2)] =
          make_float4(p[ch * 4 + 0], p[ch * 4 + 1], p[ch * 4 + 2], p[ch * 4 + 3]);
    }

    // ---- h tile into registers (L2-resident, ~200cyc, consumed by Phase B) --
    float hreg[64];
    #pragma unroll
    for (int jj = 0; jj < 64; jj++)
      hreg[jj] = h[(size_t)(j0 + jj) * OUTF + lane];

    // ---- prefetch NEXT tile (HBM ~900cyc; Phase B issue ~5000cyc covers) ----
    if (jt + 64 < JRANGE) {
      const int jn = j0 + 64;
      tl = t[jn + lane];
      #pragma unroll
      for (int r = 0; r < TI; r++) {
        const size_t gidx = (size_t)(i0 + r) * N + jn + lane;
        pa[r] = adj_ad[gidx];
        pmk[r] = adj[gidx];
      }
    }

    // ---- Phase B: acc[r] += p[r][jj] * h[jj][lane] ----
    #pragma unroll
    for (int jj = 0; jj < 64; jj++) {
      const int sw = (jj >> 1) & 3;
      const float hh = hreg[jj];
      #pragma unroll
      for (int c = 0; c < 4; c++) {
        const float4 p4 = *(const float4*)&pT[jj * TI + ((c ^ sw) << 2)];
        acc[c * 4 + 0] += p4.x * hh;
        acc[c * 4 + 1] += p4.y * hh;
        acc[c * 4 + 2] += p4.z * hh;
        acc[c * 4 + 3] += p4.w * hh;
      }
    }
  }

  // ---- epilogue: reduce S, write partials ----
  #pragma unroll
  for (int r = 0; r < TI; r++) {
    float sv = S[r];
    #pragma unroll
    for (int off = 1; off < 64; off <<= 1) sv += __shfl_xor(sv, off);
    if (lane == 0) SP[(size_t)split * N + i0 + r] = sv;
    accP[(size_t)split * (N * OUTF) + (size_t)(i0 + r) * OUTF + lane] = acc[r];
  }
}

// ---------------------------------------------------------------------------
// K3: combine j-split partials, normalize, elu.
// ---------------------------------------------------------------------------
__global__ __launch_bounds__(256) void k_combine(const float* __restrict__ accP,
                                                 const float* __restrict__ SP,
                                                 float* __restrict__ out) {
  const int idx = blockIdx.x * 256 + threadIdx.x;
  const int i = idx >> 6;
  float num = 0.f, den = 0.f;
  #pragma unroll
  for (int sp = 0; sp < JSPLIT; sp++) {
    num += accP[(size_t)sp * (N * OUTF) + idx];
    den += SP[(size_t)sp * N + i];
  }
  const float x = num / den;
  out[idx] = x > 0.f ? x : expm1f(x);
}

// ---------------------------------------------------------------------------
extern "C" void kernel_launch(void* const* d_in, const int* in_sizes, int n_in,
                              void* d_out, int out_size, void* d_ws, size_t ws_size,
                              hipStream_t stream) {
  const float* input  = (const float*)d_in[0];
  const float* W      = (const float*)d_in[1];
  const float* a      = (const float*)d_in[2];
  const float* W_si   = (const float*)d_in[3];
  const float* W_ei   = (const float*)d_in[4];
  const float* adj_ad = (const float*)d_in[5];
  const int*   adj    = (const int*)d_in[6];
  float* out = (float*)d_out;
  float* ws  = (float*)d_ws;

  float* h        = ws + OFF_H;
  float* s        = ws + OFF_S;
  float* t        = ws + OFF_T;
  unsigned* tmax  = (unsigned*)(ws + OFF_TMAX);
  float* SP       = ws + OFF_SP;
  float* accP     = ws + OFF_ACC;

  hipMemsetAsync(tmax, 0, 4, stream);
  k_precompute<<<N / 4, 64, 0, stream>>>(input, W, a, h, s, t);
  k_tmax<<<N / 512, 512, 0, stream>>>(t, tmax);
  k_attn<<<(N / TI) * JSPLIT, 64, 0, stream>>>(h, s, t, tmax, W_si, W_ei,
                                               adj_ad, adj, SP, accP);
  k_combine<<<(N * OUTF) / 256, 256, 0, stream>>>(accP, SP, out);
}

// Round 4
// 619.001 us; speedup vs baseline: 2.1933x; 1.5112x over previous
//
#include <hip/hip_runtime.h>
#include <math.h>

#define N 8192
#define IN_F 512
#define OUTF 64
#define TI 16
#define JSPLIT 4
#define JRANGE (N / JSPLIT)

typedef _Float16 f16x8 __attribute__((ext_vector_type(8)));
typedef float f32x4 __attribute__((ext_vector_type(4)));

typedef const void __attribute__((address_space(1)))* gptr_t;
typedef void __attribute__((address_space(3)))* lptr_t;

// workspace layout (floats) — total 2408464 floats = 9.63 MB (< 10.7 verified)
#define OFF_HT   0u          // hT: 64x8192 f16 = 262144 float-slots
#define OFF_S    262144u     // 8192
#define OFF_T    270336u     // 8192
#define OFF_TMAX 278528u     // 16
#define OFF_SP   278544u     // 4*8192
#define OFF_ACC  311312u     // 4*524288

__device__ __forceinline__ unsigned enc_f32(float f) {
  unsigned b = __float_as_uint(f);
  return b ^ ((unsigned)((int)b >> 31) | 0x80000000u);
}

// ---------------------------------------------------------------------------
// K1: hT[f][j] = (f16)(input@W)[j][f], s = h@a1, t = h@a2.
// Lane l holds h[i0+r][l] for r=0..3 -> one dwordx2 write to hT row l. No f32 h.
// ---------------------------------------------------------------------------
__global__ __launch_bounds__(64) void k_precompute(
    const float* __restrict__ input, const float* __restrict__ W,
    const float* __restrict__ a, _Float16* __restrict__ hT,
    float* __restrict__ s, float* __restrict__ t) {
  const int lane = threadIdx.x;
  const int i0 = blockIdx.x * 4;

  float acc[4] = {0.f, 0.f, 0.f, 0.f};
  for (int c = 0; c < IN_F; c += 4) {
    const float w0 = W[(c + 0) * OUTF + lane];
    const float w1 = W[(c + 1) * OUTF + lane];
    const float w2 = W[(c + 2) * OUTF + lane];
    const float w3 = W[(c + 3) * OUTF + lane];
    #pragma unroll
    for (int r = 0; r < 4; r++) {
      const float4 iv = *(const float4*)(input + (size_t)(i0 + r) * IN_F + c);
      acc[r] += iv.x * w0 + iv.y * w1 + iv.z * w2 + iv.w * w3;
    }
  }

  union { _Float16 f[4]; uint2 u; } pk;
  #pragma unroll
  for (int r = 0; r < 4; r++) pk.f[r] = (_Float16)acc[r];
  *(uint2*)(hT + (size_t)lane * N + i0) = pk.u;

  const float a1v = a[lane];
  const float a2v = a[OUTF + lane];
  #pragma unroll
  for (int r = 0; r < 4; r++) {
    float sv = acc[r] * a1v;
    float tv = acc[r] * a2v;
    #pragma unroll
    for (int off = 1; off < 64; off <<= 1) {
      sv += __shfl_xor(sv, off);
      tv += __shfl_xor(tv, off);
    }
    if (lane == 0) {
      s[i0 + r] = sv;
      t[i0 + r] = tv;
    }
  }
}

// ---------------------------------------------------------------------------
// K1.5: tmax via atomicMax on monotone-encoded uint (memset-0 init).
// ---------------------------------------------------------------------------
__global__ __launch_bounds__(512) void k_tmax(const float* __restrict__ t,
                                              unsigned* __restrict__ tmax) {
  __shared__ float red[8];
  const int tid = threadIdx.x;
  float m = t[blockIdx.x * 512 + tid];
  #pragma unroll
  for (int off = 1; off < 64; off <<= 1) m = fmaxf(m, __shfl_xor(m, off));
  if ((tid & 63) == 0) red[tid >> 6] = m;
  __syncthreads();
  if (tid == 0) {
    #pragma unroll
    for (int w = 1; w < 8; w++) m = fmaxf(m, red[w]);
    atomicMax(tmax, enc_f32(m));
  }
}

// ---------------------------------------------------------------------------
// K2: MFMA attention partials. 1 wave/block, 16 rows x JRANGE.
// adj/adj_ad staged to LDS via global_load_lds (dbuf, vmcnt(8) pipeline);
// Phase A computes p directly in MFMA A-fragment layout (no transpose);
// B-fragments = contiguous b128 from hT (L2-resident).
// LDS chunk mapping: element (r,jj) at float idx (jj>>4)*256+((jj>>2)&3)*64+r*4.
// ---------------------------------------------------------------------------
__global__ __launch_bounds__(64) void k_attn(
    const _Float16* __restrict__ hT, const float* __restrict__ s,
    const float* __restrict__ t, const unsigned* __restrict__ tmaxp,
    const float* __restrict__ W_si, const float* __restrict__ W_ei,
    const float* __restrict__ adj_ad, const int* __restrict__ adj,
    float* __restrict__ SP, float* __restrict__ accP) {
  __shared__ __align__(16) float bufA[2][1024];
  __shared__ __align__(16) int   bufM[2][1024];

  const int lane = threadIdx.x;
  const int q = lane >> 4;
  const int m = lane & 15;
  const int wid = blockIdx.x;
  const int split = wid & (JSPLIT - 1);
  const int i0 = (wid >> 2) * TI;
  const int jb = split * JRANGE;

  const float aei = fabsf(W_ei[0]);
  const float asi = fabsf(W_si[0]);
  const unsigned te = *tmaxp;
  const float tm = __uint_as_float((te & 0x80000000u) ? (te ^ 0x80000000u) : ~te);

  const float sr = s[i0 + m];
  const float xm = sr + tm;
  const float Mr = aei * fmaxf(xm, 0.2f * xm) + asi;  // row upper bound on e

  float S = 0.f;
  f32x4 acc[4];
  #pragma unroll
  for (int nb = 0; nb < 4; nb++) acc[nb] = (f32x4){0.f, 0.f, 0.f, 0.f};

  // per-lane staging source: row i0+m, chunk q (16B) within each k-group
  const size_t stage_ofs = (size_t)(i0 + m) * N + (size_t)(q * 4);

  #define STAGE(b, j0s)                                                        \
    {                                                                          \
      _Pragma("unroll") for (int k = 0; k < 4; k++) {                          \
        __builtin_amdgcn_global_load_lds(                                      \
            (gptr_t)(adj_ad + stage_ofs + (j0s) + k * 16),                     \
            (lptr_t)&bufA[b][k * 256], 16, 0, 0);                              \
      }                                                                        \
      _Pragma("unroll") for (int k = 0; k < 4; k++) {                          \
        __builtin_amdgcn_global_load_lds(                                      \
            (gptr_t)(adj + stage_ofs + (j0s) + k * 16),                        \
            (lptr_t)&bufM[b][k * 256], 16, 0, 0);                              \
      }                                                                        \
    }

  STAGE(0, jb);
  int buf = 0;

  for (int jt = 0; jt < JRANGE; jt += 64) {
    const int j0 = jb + jt;

    if (jt + 64 < JRANGE) {
      STAGE(buf ^ 1, j0 + 64);
      // in-order vmcnt retire: <=8 outstanding ==> cur buffer's 8 loads done
      __builtin_amdgcn_s_waitcnt(0xF78);  // vmcnt(8), lgkm/exp untouched
    } else {
      __builtin_amdgcn_s_waitcnt(0xF70);  // vmcnt(0)
    }

    #pragma unroll
    for (int c = 0; c < 2; c++) {
      const int jc0 = c * 8 + q * 2;  // 16B-chunk index (j-run of 4)
      #define LIDX(jc) ((((jc) >> 2) * 256) + (((jc) & 3) * 64) + m * 4)
      const float4 a0 = *(const float4*)&bufA[buf][LIDX(jc0)];
      const float4 a1 = *(const float4*)&bufA[buf][LIDX(jc0 + 1)];
      const int4 k0 = *(const int4*)&bufM[buf][LIDX(jc0)];
      const int4 k1 = *(const int4*)&bufM[buf][LIDX(jc0 + 1)];
      const float4 t0 = *(const float4*)&t[j0 + c * 32 + q * 8];
      const float4 t1 = *(const float4*)&t[j0 + c * 32 + q * 8 + 4];

      const float ad[8] = {a0.x, a0.y, a0.z, a0.w, a1.x, a1.y, a1.z, a1.w};
      const int mk[8] = {k0.x, k0.y, k0.z, k0.w, k1.x, k1.y, k1.z, k1.w};
      const float tv[8] = {t0.x, t0.y, t0.z, t0.w, t1.x, t1.y, t1.z, t1.w};

      f16x8 fa;
      #pragma unroll
      for (int e = 0; e < 8; e++) {
        const float x = sr + tv[e];
        const float ee = aei * fmaxf(x, 0.2f * x) + asi * ad[e];
        const float p = (mk[e] > 0) ? __expf(ee - Mr) : 0.f;
        S += p;
        fa[e] = (_Float16)p;
      }

      #pragma unroll
      for (int nb = 0; nb < 4; nb++) {
        const f16x8 fb = *(const f16x8*)&hT[(size_t)(nb * 16 + m) * N + j0 +
                                            c * 32 + q * 8];
        acc[nb] = __builtin_amdgcn_mfma_f32_16x16x32_f16(fa, fb, acc[nb], 0, 0, 0);
      }
    }
    buf ^= 1;
  }

  // S: lane holds partial over its (m, q-slice) — sum over q
  S += __shfl_xor(S, 16);
  S += __shfl_xor(S, 32);
  if (lane < 16) SP[(size_t)split * N + i0 + lane] = S;

  // C/D layout: col = lane&15, row = q*4 + reg
  #pragma unroll
  for (int nb = 0; nb < 4; nb++) {
    #pragma unroll
    for (int reg = 0; reg < 4; reg++) {
      accP[((size_t)split * N + i0 + q * 4 + reg) * OUTF + nb * 16 + m] =
          acc[nb][reg];
    }
  }
}

// ---------------------------------------------------------------------------
// K3: combine j-split partials, normalize, elu.
// ---------------------------------------------------------------------------
__global__ __launch_bounds__(256) void k_combine(const float* __restrict__ accP,
                                                 const float* __restrict__ SP,
                                                 float* __restrict__ out) {
  const int idx = blockIdx.x * 256 + threadIdx.x;
  const int i = idx >> 6;
  float num = 0.f, den = 0.f;
  #pragma unroll
  for (int sp = 0; sp < JSPLIT; sp++) {
    num += accP[(size_t)sp * (N * OUTF) + idx];
    den += SP[(size_t)sp * N + i];
  }
  const float x = num / den;
  out[idx] = x > 0.f ? x : expm1f(x);
}

// ---------------------------------------------------------------------------
extern "C" void kernel_launch(void* const* d_in, const int* in_sizes, int n_in,
                              void* d_out, int out_size, void* d_ws, size_t ws_size,
                              hipStream_t stream) {
  const float* input  = (const float*)d_in[0];
  const float* W      = (const float*)d_in[1];
  const float* a      = (const float*)d_in[2];
  const float* W_si   = (const float*)d_in[3];
  const float* W_ei   = (const float*)d_in[4];
  const float* adj_ad = (const float*)d_in[5];
  const int*   adj    = (const int*)d_in[6];
  float* out = (float*)d_out;
  float* ws  = (float*)d_ws;

  _Float16* hT   = (_Float16*)(ws + OFF_HT);
  float* s       = ws + OFF_S;
  float* t       = ws + OFF_T;
  unsigned* tmax = (unsigned*)(ws + OFF_TMAX);
  float* SP      = ws + OFF_SP;
  float* accP    = ws + OFF_ACC;

  hipMemsetAsync(tmax, 0, 4, stream);
  k_precompute<<<N / 4, 64, 0, stream>>>(input, W, a, hT, s, t);
  k_tmax<<<N / 512, 512, 0, stream>>>(t, tmax);
  k_attn<<<(N / TI) * JSPLIT, 64, 0, stream>>>(hT, s, t, tmax, W_si, W_ei,
                                               adj_ad, adj, SP, accP);
  k_combine<<<(N * OUTF) / 256, 256, 0, stream>>>(accP, SP, out);
}